// Round 1
// baseline (7881.816 us; speedup 1.0000x reference)
//
#include <hip/hip_runtime.h>
#include <hip/hip_bf16.h>

typedef float f32x4 __attribute__((ext_vector_type(4)));
typedef __bf16 bf16x8 __attribute__((ext_vector_type(8)));

#define BDIM 256
#define BPITCH 56            // LDS pitch (ushorts) per B column (16B-aligned, 2-way-max banks)
#define BSZ (96*BPITCH)      // per-buffer B_s ushorts
#define ASZ 1024             // per-buffer A_s ushorts (2 row-tiles * 4 quads * 16 m * 8)

__device__ __forceinline__ unsigned short f2b(float f) {
  unsigned u = __builtin_bit_cast(unsigned, f);
  unsigned r = (u + 0x7fffu + ((u >> 16) & 1u)) >> 16;   // RNE
  return (unsigned short)r;
}

// Transpose fp32 [R][C] -> bf16 [C][R]
__global__ __launch_bounds__(256) void tconv(const float* __restrict__ in,
                                             unsigned short* __restrict__ out,
                                             int R, int C) {
  __shared__ unsigned short tile[32][33];
  const int tx = threadIdx.x & 31, ty = threadIdx.x >> 5;
  const int c0 = blockIdx.x * 32, r0 = blockIdx.y * 32;
#pragma unroll
  for (int p = 0; p < 4; ++p) {
    int r = ty + p * 8;
    tile[r][tx] = f2b(in[(size_t)(r0 + r) * C + c0 + tx]);
  }
  __syncthreads();
#pragma unroll
  for (int p = 0; p < 4; ++p) {
    int cc = ty + p * 8;
    out[(size_t)(c0 + cc) * R + r0 + tx] = tile[tx][cc];
  }
}

__global__ __launch_bounds__(256) void hzero(float* __restrict__ h) {
  int i = blockIdx.x * 256 + threadIdx.x;
#pragma unroll
  for (int p = 0; p < 4; ++p) h[i + p * 65536] = 0.f;
}

// One GRU timestep. Block tile: 32 rows x 32 u-cols (96 gate-cols).
// Wave w: rows (w&1)*16..+15, col-tiles ct in {3*(w>>1)..+2}.
// ct 0,1 = z cols 0-15/16-31 ; ct 2,3 = r ; ct 4,5 = h (xh & rh kept separate).
__global__ __launch_bounds__(BDIM) void gru_step(
    const float* __restrict__ x_t,             // x + t*I, row pitch T*I = 131072
    const unsigned short* __restrict__ Wt,     // bf16 [3072][512]
    const unsigned short* __restrict__ Ut,     // bf16 [3072][1024]
    const float* __restrict__ bias,            // fp32 [2][3072]
    const float* __restrict__ h_in,            // fp32 [256][1024]
    float* __restrict__ h_out)                 // fp32 [256][1024]
{
  __shared__ unsigned short A_s[2 * ASZ];
  __shared__ unsigned short B_s[2 * BSZ];
  __shared__ float zr_s[32][64];
  __shared__ float xh_s[32][32];
  __shared__ float rh_s[32][32];

  const int tid = threadIdx.x;
  const int lane = tid & 63;
  const int w = tid >> 6;
  const int ch = w >> 1;          // col-half (tiles 0-2 vs 3-5)
  const int rhalf = w & 1;        // 16-row group
  const int u0 = blockIdx.x * 32;
  const int b0 = blockIdx.y * 32;

  // A-staging mapping: thread loads float4 x[row][k0+akg*4], writes fragment-order LDS
  const int arow = tid >> 3;      // 0..31
  const int akg = tid & 7;        // float4 chunk along k
  const int a_lds = (arow >> 4) * 512 + (akg >> 1) * 128 + (arow & 15) * 8 + (akg & 1) * 4;

  // B-staging mapping: chunk = 16B (8 bf16 along k) of one column. 384 chunks/tile.
  const int col0 = tid >> 2, q0 = tid & 3;
  const int cg0 = (col0 >> 5) * 1024 + (col0 & 31);
  const int c1i = 256 + tid;
  const int col1 = c1i >> 2, q1 = c1i & 3;
  const int cg1 = (col1 >> 5) * 1024 + (col1 & 31);

  f32x4 acc1[3], acc2[3];
#pragma unroll
  for (int j = 0; j < 3; ++j) { acc1[j] = 0.0f; acc2[j] = 0.0f; }

  float4 aR;
  uint4 bA, bB;
  // prologue prefetch: s=0 (phase 0, k0=0)
  aR = *reinterpret_cast<const float4*>(&x_t[(size_t)(b0 + arow) * 131072 + akg * 4]);
  bA = *reinterpret_cast<const uint4*>(&Wt[(size_t)(cg0 + u0) * 512 + q0 * 8]);
  if (tid < 128)
    bB = *reinterpret_cast<const uint4*>(&Wt[(size_t)(cg1 + u0) * 512 + q1 * 8]);

  const int a_frag_off = rhalf * 512 + (lane >> 4) * 128 + (lane & 15) * 8;
  const int b_frag_base = (lane & 15) * BPITCH + (lane >> 4) * 8;

  for (int s = 0; s < 48; ++s) {
    const int buf = s & 1;
    // ---- stage current prefetched regs into LDS buf ----
    {
      union { unsigned short u[4]; uint2 v; } ab;
      ab.u[0] = f2b(aR.x); ab.u[1] = f2b(aR.y); ab.u[2] = f2b(aR.z); ab.u[3] = f2b(aR.w);
      *reinterpret_cast<uint2*>(&A_s[buf * ASZ + a_lds]) = ab.v;
    }
    *reinterpret_cast<uint4*>(&B_s[buf * BSZ + col0 * BPITCH + q0 * 8]) = bA;
    if (tid < 128)
      *reinterpret_cast<uint4*>(&B_s[buf * BSZ + col1 * BPITCH + q1 * 8]) = bB;

    // ---- prefetch step s+1 ----
    if (s < 47) {
      const int sn = s + 1;
      const float* Ag;
      const unsigned short* Bt;
      int rp, K, k0;
      if (sn < 16) { Ag = x_t;  Bt = Wt; rp = 131072; K = 512;  k0 = sn * 32; }
      else         { Ag = h_in; Bt = Ut; rp = 1024;   K = 1024; k0 = (sn - 16) * 32; }
      aR = *reinterpret_cast<const float4*>(&Ag[(size_t)(b0 + arow) * rp + k0 + akg * 4]);
      bA = *reinterpret_cast<const uint4*>(&Bt[(size_t)(cg0 + u0) * K + k0 + q0 * 8]);
      if (tid < 128)
        bB = *reinterpret_cast<const uint4*>(&Bt[(size_t)(cg1 + u0) * K + k0 + q1 * 8]);
    }
    __syncthreads();

    // ---- compute from LDS buf ----
    bf16x8 af = *reinterpret_cast<const bf16x8*>(&A_s[buf * ASZ + a_frag_off]);
    if (s < 16) {
#pragma unroll
      for (int j = 0; j < 3; ++j) {
        const int ct = ch * 3 + j;
        bf16x8 bfv = *reinterpret_cast<const bf16x8*>(&B_s[buf * BSZ + ct * 16 * BPITCH + b_frag_base]);
        acc1[j] = __builtin_amdgcn_mfma_f32_16x16x32_bf16(af, bfv, acc1[j], 0, 0, 0);
      }
    } else {
#pragma unroll
      for (int j = 0; j < 3; ++j) {
        const int ct = ch * 3 + j;
        bf16x8 bfv = *reinterpret_cast<const bf16x8*>(&B_s[buf * BSZ + ct * 16 * BPITCH + b_frag_base]);
        acc2[j] = __builtin_amdgcn_mfma_f32_16x16x32_bf16(af, bfv, acc2[j], 0, 0, 0);
      }
    }
  }

  // ---- epilogue: dump accs (C-layout col=lane&15, row=(lane>>4)*4+reg) ----
  __syncthreads();   // ensure all waves done with their last compute before reuse patterns
  const int trow_base = rhalf * 16 + ((lane >> 4) << 2);
  const int tcol = lane & 15;
#pragma unroll
  for (int j = 0; j < 3; ++j) {
    const int ct = ch * 3 + j;
#pragma unroll
    for (int v = 0; v < 4; ++v) {
      const int r = trow_base + v;
      const float p1 = acc1[j][v], p2 = acc2[j][v];
      if (ct < 2)       zr_s[r][ct * 16 + tcol] = p1 + p2;          // z pre-act (x+h parts)
      else if (ct < 4)  zr_s[r][32 + (ct - 2) * 16 + tcol] = p1 + p2; // r pre-act
      else { xh_s[r][(ct - 4) * 16 + tcol] = p1; rh_s[r][(ct - 4) * 16 + tcol] = p2; }
    }
  }
  __syncthreads();

#pragma unroll
  for (int p = 0; p < 4; ++p) {
    const int idx = p * 256 + tid;
    const int r = idx >> 5, cu = idx & 31;
    const int u = u0 + cu;
    const float zpre = zr_s[r][cu]      + bias[u]        + bias[3072 + u];
    const float rpre = zr_s[r][32 + cu] + bias[1024 + u] + bias[4096 + u];
    const float xh   = xh_s[r][cu]      + bias[2048 + u];
    const float rh   = rh_s[r][cu]      + bias[5120 + u];
    const float z  = 1.f / (1.f + expf(-zpre));
    const float rr = 1.f / (1.f + expf(-rpre));
    const float hh = tanhf(fmaf(rr, rh, xh));
    const float hold = h_in[(size_t)(b0 + r) * 1024 + u];
    h_out[(size_t)(b0 + r) * 1024 + u] = fmaf(z, hold - hh, hh);
  }
}

extern "C" void kernel_launch(void* const* d_in, const int* in_sizes, int n_in,
                              void* d_out, int out_size, void* d_ws, size_t ws_size,
                              hipStream_t stream) {
  (void)in_sizes; (void)n_in; (void)out_size; (void)ws_size;
  const float* x    = (const float*)d_in[0];   // (256,256,512)
  const float* Wk   = (const float*)d_in[1];   // (512,3072)
  const float* Rk   = (const float*)d_in[2];   // (1024,3072)
  const float* bias = (const float*)d_in[3];   // (2,3072)
  float* out = (float*)d_out;

  char* ws = (char*)d_ws;
  unsigned short* Wt = (unsigned short*)ws;                          // 3072*512 bf16
  unsigned short* Ut = (unsigned short*)(ws + (size_t)3072 * 512 * 2);  // 3072*1024 bf16
  float* hA = (float*)(ws + (size_t)3072 * 512 * 2 + (size_t)3072 * 1024 * 2);
  float* hB = hA + 256 * 1024;

  tconv<<<dim3(96, 16), 256, 0, stream>>>(Wk, Wt, 512, 3072);
  tconv<<<dim3(96, 32), 256, 0, stream>>>(Rk, Ut, 1024, 3072);
  hzero<<<256, 256, 0, stream>>>(hA);

  dim3 grid(32, 8);   // 1024/32 u-tiles, 256/32 row-tiles
  for (int t = 0; t < 256; ++t) {
    const float* hin = (t & 1) ? hB : hA;
    float* hout = (t == 255) ? out : ((t & 1) ? hA : hB);
    gru_step<<<grid, 256, 0, stream>>>(x + (size_t)t * 512, Wt, Ut, bias, hin, hout);
  }
}

// Round 2
// 4957.463 us; speedup vs baseline: 1.5899x; 1.5899x over previous
//
#include <hip/hip_runtime.h>
#include <hip/hip_bf16.h>

typedef float f32x4 __attribute__((ext_vector_type(4)));
typedef __bf16 bf16x8 __attribute__((ext_vector_type(8)));

__device__ __forceinline__ unsigned short f2b(float f) {
  unsigned u = __builtin_bit_cast(unsigned, f);
  unsigned r = (u + 0x7fffu + ((u >> 16) & 1u)) >> 16;   // RNE
  return (unsigned short)r;
}
__device__ __forceinline__ float b2f(unsigned short s) {
  return __builtin_bit_cast(float, ((unsigned)s) << 16);
}

// ---------------- transpose fp32 [R][C] -> bf16 [C][R] ----------------
__global__ __launch_bounds__(256) void tconv(const float* __restrict__ in,
                                             unsigned short* __restrict__ out,
                                             int R, int C) {
  __shared__ unsigned short tile[32][33];
  const int tx = threadIdx.x & 31, ty = threadIdx.x >> 5;
  const int c0 = blockIdx.x * 32, r0 = blockIdx.y * 32;
#pragma unroll
  for (int p = 0; p < 4; ++p) {
    int r = ty + p * 8;
    tile[r][tx] = f2b(in[(size_t)(r0 + r) * C + c0 + tx]);
  }
  __syncthreads();
#pragma unroll
  for (int p = 0; p < 4; ++p) {
    int cc = ty + p * 8;
    out[(size_t)(c0 + cc) * R + r0 + tx] = tile[tx][cc];
  }
}

// ---------------- combined bias prep: [4][1024] = bz, br, bhi, bhr ----
__global__ __launch_bounds__(256) void bprep(const float* __restrict__ bias,
                                             float* __restrict__ bc) {
  const int u = blockIdx.x * 256 + threadIdx.x;  // 0..1023
  bc[u]        = bias[u]        + bias[3072 + u];
  bc[1024 + u] = bias[1024 + u] + bias[4096 + u];
  bc[2048 + u] = bias[2048 + u];
  bc[3072 + u] = bias[5120 + u];
}

// ---------------- h init: zero bf16 + fp32 state ----------------------
__global__ __launch_bounds__(256) void hinit(unsigned short* __restrict__ hbf,
                                             float* __restrict__ h32) {
  const int id = blockIdx.x * 256 + threadIdx.x;  // 65536 threads
  ((uint2*)hbf)[id] = make_uint2(0u, 0u);
  ((float4*)h32)[id] = make_float4(0.f, 0.f, 0.f, 0.f);
}

// ---------------- x projection chunk GEMM ------------------------------
// Computes x_proj rows r = tl*256 + b (tl in chunk, b = batch) times Wt.
// Out layout (bf16): xp[tl][cg(64)][gate(3)][b(256)][u16(16)]
__global__ __launch_bounds__(256) void xproj(
    const float* __restrict__ x,              // [256][256][512]
    const unsigned short* __restrict__ Wt,    // bf16 [3072][512]
    unsigned short* __restrict__ xp,
    int t0)
{
  __shared__ unsigned short A_s[128 * 32];
  __shared__ unsigned short B_s[128 * 32];
  const int tid = threadIdx.x;
  const int lane = tid & 63, w = tid >> 6;
  const int n0 = blockIdx.x * 128;
  const int r0 = blockIdx.y * 128;
  const int wm = w >> 1, wn = w & 1;
  const int u16l = lane & 15, kq = lane >> 4;

  f32x4 acc[4][4];
#pragma unroll
  for (int i = 0; i < 4; ++i)
#pragma unroll
    for (int j = 0; j < 4; ++j) acc[i][j] = 0.0f;

  const int srow = tid >> 1;     // 0..127
  const int skh = tid & 1;       // k half (16 elems)
  const int arow_g = r0 + srow;
  const int a_tl = arow_g >> 8, a_b = arow_g & 255;
  const float* asrc = x + ((size_t)a_b * 256 + t0 + a_tl) * 512 + skh * 16;
  const unsigned short* bsrc = Wt + (size_t)(n0 + srow) * 512 + skh * 16;

  for (int kt = 0; kt < 16; ++kt) {
    const int k0 = kt * 32;
    float4 af0 = *(const float4*)(asrc + k0);
    float4 af1 = *(const float4*)(asrc + k0 + 4);
    float4 af2 = *(const float4*)(asrc + k0 + 8);
    float4 af3 = *(const float4*)(asrc + k0 + 12);
    uint4 bv0 = *(const uint4*)(bsrc + k0);
    uint4 bv1 = *(const uint4*)(bsrc + k0 + 8);
    union { unsigned short s[8]; uint4 v; } p0, p1;
    p0.s[0] = f2b(af0.x); p0.s[1] = f2b(af0.y); p0.s[2] = f2b(af0.z); p0.s[3] = f2b(af0.w);
    p0.s[4] = f2b(af1.x); p0.s[5] = f2b(af1.y); p0.s[6] = f2b(af1.z); p0.s[7] = f2b(af1.w);
    p1.s[0] = f2b(af2.x); p1.s[1] = f2b(af2.y); p1.s[2] = f2b(af2.z); p1.s[3] = f2b(af2.w);
    p1.s[4] = f2b(af3.x); p1.s[5] = f2b(af3.y); p1.s[6] = f2b(af3.z); p1.s[7] = f2b(af3.w);
    __syncthreads();   // previous compute done before overwrite
    *(uint4*)&A_s[srow * 32 + skh * 16]     = p0.v;
    *(uint4*)&A_s[srow * 32 + skh * 16 + 8] = p1.v;
    *(uint4*)&B_s[srow * 32 + skh * 16]     = bv0;
    *(uint4*)&B_s[srow * 32 + skh * 16 + 8] = bv1;
    __syncthreads();
    bf16x8 afr[4], bfr[4];
#pragma unroll
    for (int i = 0; i < 4; ++i)
      afr[i] = *(const bf16x8*)&A_s[(wm * 64 + i * 16 + u16l) * 32 + kq * 8];
#pragma unroll
    for (int j = 0; j < 4; ++j)
      bfr[j] = *(const bf16x8*)&B_s[(wn * 64 + j * 16 + u16l) * 32 + kq * 8];
#pragma unroll
    for (int i = 0; i < 4; ++i)
#pragma unroll
      for (int j = 0; j < 4; ++j)
        acc[i][j] = __builtin_amdgcn_mfma_f32_16x16x32_bf16(afr[i], bfr[j], acc[i][j], 0, 0, 0);
  }

#pragma unroll
  for (int i = 0; i < 4; ++i)
#pragma unroll
    for (int j = 0; j < 4; ++j)
#pragma unroll
      for (int v = 0; v < 4; ++v) {
        const int gr = r0 + wm * 64 + i * 16 + kq * 4 + v;
        const int gc = n0 + wn * 64 + j * 16 + u16l;
        const int gate = gc >> 10, cg = (gc >> 4) & 63, uu = gc & 15;
        const int tl = gr >> 8, b = gr & 255;
        xp[(size_t)tl * 786432 + ((size_t)(cg * 3 + gate) * 256 + b) * 16 + uu] = f2b(acc[i][j][v]);
      }
}

// ---------------- one GRU timestep (barrier-free K-loop) ---------------
// 256 blocks x 256 thr. Wave tile: 16 rows x 48 gate-cols (3 gates of one
// u16 group). cg = blockIdx>>2 (4 waves share cg -> L1 dedup of U reads).
__global__ __launch_bounds__(256) void gru_step(
    const unsigned short* __restrict__ xp_t,   // [64][3][256][16] bf16
    const unsigned short* __restrict__ Ut,     // bf16 [3072][1024]
    const float* __restrict__ biasC,           // [4][1024]
    const unsigned short* __restrict__ hbf_in, // bf16 [256][1024]
    const float* __restrict__ h32_in,          // fp32 [256][1024]
    unsigned short* __restrict__ hbf_out,
    float* __restrict__ h32_out)
{
  const int tid = threadIdx.x;
  const int lane = tid & 63, w = tid >> 6;
  const int cg = blockIdx.x >> 2;
  const int rg = ((blockIdx.x & 3) << 2) | w;
  const int r0 = rg << 4;
  const int u16l = lane & 15, kq = lane >> 4;

  const unsigned short* apt = hbf_in + ((size_t)(r0 + u16l) << 10) + kq * 8;
  const unsigned short* bpt = Ut + ((size_t)((cg << 4) + u16l) << 10) + kq * 8;

  f32x4 acc[3];
#pragma unroll
  for (int g = 0; g < 3; ++g) acc[g] = 0.0f;

  bf16x8 pa[3], pb[3][3];
#pragma unroll
  for (int i = 0; i < 3; ++i) {
    pa[i] = *(const bf16x8*)(apt + i * 32);
#pragma unroll
    for (int g = 0; g < 3; ++g)
      pb[i][g] = *(const bf16x8*)(bpt + ((size_t)g << 20) + i * 32);
  }

#pragma unroll
  for (int ks = 0; ks < 32; ++ks) {
    const int sl = ks % 3;
    const bf16x8 af = pa[sl];
    const bf16x8 b0 = pb[sl][0], b1 = pb[sl][1], b2 = pb[sl][2];
    if (ks < 29) {
      pa[sl] = *(const bf16x8*)(apt + (ks + 3) * 32);
#pragma unroll
      for (int g = 0; g < 3; ++g)
        pb[sl][g] = *(const bf16x8*)(bpt + ((size_t)g << 20) + (ks + 3) * 32);
    }
    acc[0] = __builtin_amdgcn_mfma_f32_16x16x32_bf16(af, b0, acc[0], 0, 0, 0);
    acc[1] = __builtin_amdgcn_mfma_f32_16x16x32_bf16(af, b1, acc[1], 0, 0, 0);
    acc[2] = __builtin_amdgcn_mfma_f32_16x16x32_bf16(af, b2, acc[2], 0, 0, 0);
  }

  // epilogue: C-layout col=lane&15, row=kq*4+v
  const int cu = (cg << 4) + u16l;
  const float bz  = biasC[cu];
  const float br  = biasC[1024 + cu];
  const float bhi = biasC[2048 + cu];
  const float bhr = biasC[3072 + cu];
#pragma unroll
  for (int v = 0; v < 4; ++v) {
    const int r = r0 + (kq << 2) + v;
    const float xz = b2f(xp_t[((size_t)(cg * 3 + 0) * 256 + r) * 16 + u16l]);
    const float xr = b2f(xp_t[((size_t)(cg * 3 + 1) * 256 + r) * 16 + u16l]);
    const float xh = b2f(xp_t[((size_t)(cg * 3 + 2) * 256 + r) * 16 + u16l]);
    const float hold = h32_in[(size_t)r * 1024 + cu];
    const float zpre = acc[0][v] + xz + bz;
    const float rpre = acc[1][v] + xr + br;
    const float rh   = acc[2][v] + bhr;
    const float z  = 1.f / (1.f + __expf(-zpre));
    const float rr = 1.f / (1.f + __expf(-rpre));
    const float hp = xh + bhi + rr * rh;
    const float e2 = __expf(2.f * hp);
    const float hh = 1.f - 2.f / (e2 + 1.f);
    const float hnew = hh + z * (hold - hh);
    h32_out[(size_t)r * 1024 + cu] = hnew;
    hbf_out[(size_t)r * 1024 + cu] = f2b(hnew);
  }
}

extern "C" void kernel_launch(void* const* d_in, const int* in_sizes, int n_in,
                              void* d_out, int out_size, void* d_ws, size_t ws_size,
                              hipStream_t stream) {
  (void)in_sizes; (void)n_in; (void)out_size;
  const float* x    = (const float*)d_in[0];   // (256,256,512)
  const float* Wk   = (const float*)d_in[1];   // (512,3072)
  const float* Rk   = (const float*)d_in[2];   // (1024,3072)
  const float* bias = (const float*)d_in[3];   // (2,3072)
  float* out = (float*)d_out;

  char* ws = (char*)d_ws;
  unsigned short* Wt    = (unsigned short*)(ws + 0);         // 3,145,728 B
  unsigned short* Ut    = (unsigned short*)(ws + 3145728);   // 6,291,456 B
  float*          biasC = (float*)(ws + 9437184);            // 16,384 B
  unsigned short* hbf0  = (unsigned short*)(ws + 9453568);   // 524,288 B
  unsigned short* hbf1  = (unsigned short*)(ws + 9977856);   // 524,288 B
  float*          h320  = (float*)(ws + 10502144);           // 1,048,576 B
  float*          h321  = (float*)(ws + 11550720);           // 1,048,576 B
  unsigned short* xp    = (unsigned short*)(ws + 12599296);  // CH * 1,572,864 B

  const size_t fixed_end = 12599296;
  int CH = 256;
  while (CH > 1 && fixed_end + (size_t)CH * 1572864 > ws_size) CH >>= 1;

  tconv<<<dim3(96, 16), 256, 0, stream>>>(Wk, Wt, 512, 3072);
  tconv<<<dim3(96, 32), 256, 0, stream>>>(Rk, Ut, 1024, 3072);
  bprep<<<4, 256, 0, stream>>>(bias, biasC);
  hinit<<<256, 256, 0, stream>>>(hbf0, h320);

  unsigned short* hbf[2] = {hbf0, hbf1};
  float* h32[2] = {h320, h321};

  const int nch = 256 / CH;
  for (int c = 0; c < nch; ++c) {
    xproj<<<dim3(24, CH * 2), 256, 0, stream>>>(x, Wt, xp, c * CH);
    for (int tl = 0; tl < CH; ++tl) {
      const int t = c * CH + tl;
      gru_step<<<256, 256, 0, stream>>>(
          xp + (size_t)tl * 786432, Ut, biasC,
          hbf[t & 1], h32[t & 1],
          hbf[(t + 1) & 1],
          (t == 255) ? out : h32[(t + 1) & 1]);
    }
  }
}